// Round 9
// baseline (124.166 us; speedup 1.0000x reference)
//
#include <hip/hip_runtime.h>
#include <hip/hip_cooperative_groups.h>

namespace cg = cooperative_groups;

#define HH 2048
#define WW 2048
#define WPR 32            // 64-bit words per image row
#define NPIX (HH * WW)
#define NWORDS (HH * WPR)

typedef unsigned long long u64;
typedef unsigned int u32;

// ---------------- global union-find (ECL-CC style, lock-free) ----------------
__device__ inline int findRoot(int* __restrict__ f, int i) {
    int p = __hip_atomic_load(&f[i], __ATOMIC_RELAXED, __HIP_MEMORY_SCOPE_AGENT);
    while (p != i) {
        int gp = __hip_atomic_load(&f[p], __ATOMIC_RELAXED, __HIP_MEMORY_SCOPE_AGENT);
        if (gp != p)
            __hip_atomic_store(&f[i], gp, __ATOMIC_RELAXED, __HIP_MEMORY_SCOPE_AGENT);
        i = p; p = gp;
    }
    return i;
}

__device__ inline void unite(int* __restrict__ f, int a, int b) {
    int ra = findRoot(f, a), rb = findRoot(f, b);
    while (ra != rb) {
        if (ra > rb) { int t = ra; ra = rb; rb = t; }
        int old = atomicCAS(&f[rb], rb, ra);
        if (old == rb || old == ra) return;
        rb = findRoot(f, old);
    }
}

__device__ inline int findRootRO(const int* __restrict__ f, int i) {
    int p = __hip_atomic_load(&f[i], __ATOMIC_RELAXED, __HIP_MEMORY_SCOPE_AGENT);
    while (true) {
        int gp = __hip_atomic_load(&f[p], __ATOMIC_RELAXED, __HIP_MEMORY_SCOPE_AGENT);
        if (gp == p) return p;
        p = gp;
    }
}

// ---------------- LDS-local union-find ----------------
__device__ inline int findRootL(volatile int* fl, int i) {
    int p = fl[i];
    while (p != i) {
        int gp = fl[p];
        if (gp != p) fl[i] = gp;
        i = p; p = gp;
    }
    return i;
}

__device__ inline void uniteL(int* fl, int a, int b) {
    int ra = findRootL(fl, a), rb = findRootL(fl, b);
    while (ra != rb) {
        if (ra > rb) { int t = ra; ra = rb; rb = t; }
        int old = atomicCAS(&fl[rb], rb, ra);
        if (old == rb || old == ra) return;
        rb = findRootL(fl, old);
    }
}

// exact direction class via tan(22.5)=sqrt2-1, tan(67.5)=sqrt2+1 (int32 exact).
__device__ inline int dirClass(int gxv, int gyv) {
    int ay = gyv, ax = gxv;
    if (ay < 0) { ay = -ay; ax = -ax; }
    if (ay == 0) return 0;
    if (ax > 0) {
        int s = ay + ax, q = 2 * ax * ax;
        if (s * s < q) return 0;
        int t = ay - ax;
        return (t < 0 || t * t < q) ? 1 : 2;
    }
    if (ax == 0) return 2;
    int h = -ax, s = ay + h, q = 2 * h * h;
    if (s * s < q) return 0;
    int t = ay - h;
    return (t > 0 && t * t > q) ? 2 : 3;
}

// ---------------- Kernel 1 (fused): quantize+Sobel+NMS+thresholds+LOCAL CC ----------
// 64x64 tile per block, 512 threads. Local node 0 is a VIRTUAL strong super-root.
// f is written SPARSELY: only entries that later chases can read —
// weak px of border-touching comps (pend ⊂ that set; boundary only starts chases
// from tile-border px, whose comps are touched by definition) and border px of
// strong comps (value 0 -> chase hits f[0]). f[0]=0 written by block (0,0).
__global__ __launch_bounds__(512) void canny_tile(
    const float* __restrict__ x, u64* __restrict__ weakG,
    u64* __restrict__ edgeBits, u64* __restrict__ pendBits, int* __restrict__ f)
{
    __shared__ int imgS[68 * 68];            // quantized img, halo 2; REUSED as fl[4097]
    __shared__ unsigned short magS[66 * 66]; // (cls<<12) | mag  (mag<=2040<4096)
    __shared__ u64 wRow[64], sRow[64];
    __shared__ unsigned char touched[4097];
    int* fl = imgS;

    const int tid = threadIdx.x;
    const int x0 = blockIdx.x * 64;
    const int y0 = blockIdx.y * 64;

    if (blockIdx.x == 0 && blockIdx.y == 0 && tid == 0) f[0] = 0;

    // ---- stage 68x68 quantized image. (int)(v*255) == floor for v in [0,1]. ----
    if (x0 >= 4 && x0 + 68 <= WW) {
        // fast path: aligned float4 window [x0-4, x0+68), 18 quads x 68 rows
        for (int t = tid; t < 18 * 68; t += 512) {
            int r = t / 18, k = t - r * 18;
            int gy = y0 - 2 + r; gy = gy < 0 ? 0 : (gy > HH - 1 ? HH - 1 : gy);
            float4 v = *reinterpret_cast<const float4*>(x + (size_t)gy * WW + (x0 - 4) + 4 * k);
            int c0 = 4 * k - 2;                 // imgS col of v.x
            if (c0 >= 0)            imgS[r * 68 + c0]     = (int)(v.x * 255.0f);
            if ((unsigned)(c0 + 1) < 68) imgS[r * 68 + c0 + 1] = (int)(v.y * 255.0f);
            if ((unsigned)(c0 + 2) < 68) imgS[r * 68 + c0 + 2] = (int)(v.z * 255.0f);
            if (c0 + 3 < 68)        imgS[r * 68 + c0 + 3] = (int)(v.w * 255.0f);
        }
    } else {
        for (int idx = tid; idx < 68 * 68; idx += 512) {
            int r = idx / 68, c = idx - r * 68;
            int gy = y0 - 2 + r; gy = gy < 0 ? 0 : (gy > HH - 1 ? HH - 1 : gy);
            int gx = x0 - 2 + c; gx = gx < 0 ? 0 : (gx > WW - 1 ? WW - 1 : gx);
            imgS[idx] = (int)(x[(size_t)gy * WW + gx] * 255.0f);
        }
    }
    __syncthreads();

    // ---- Sobel once per 66x66 item: pack (cls<<12)|mag (integer exact) ----
    for (int idx = tid; idx < 66 * 66; idx += 512) {
        int r = idx / 66, c = idx - r * 66;
        int i0 = r * 68 + c;
        int a00 = imgS[i0],       a01 = imgS[i0 + 1],   a02 = imgS[i0 + 2];
        int a10 = imgS[i0 + 68],                        a12 = imgS[i0 + 70];
        int a20 = imgS[i0 + 136], a21 = imgS[i0 + 137], a22 = imgS[i0 + 138];
        int gxv = (a02 + 2 * a12 + a22) - (a00 + 2 * a10 + a20);
        int gyv = (a20 + 2 * a21 + a22) - (a00 + 2 * a01 + a02);
        int mag = abs(gxv) + abs(gyv);
        int cls = dirClass(gxv, gyv);
        magS[idx] = (unsigned short)((cls << 12) | mag);
    }
    __syncthreads();   // imgS dead (NMS reads only magS) -> fl aliases imgS

    // ---- NMS + thresholds; fl/touched init in same phase ----
    const int lane = tid & 63;
    const int wv = tid >> 6;
    for (int i = 0; i < 8; ++i) {
        int rr = wv * 8 + i;
        int gyp = y0 + rr;
        int mc = (rr + 1) * 66 + lane + 1;
        int mv = magS[mc];
        int cls = mv >> 12;
        int mag = mv & 0xFFF;
        int d1 = (cls == 0) ? -1 : 64 + cls;
        int n1 = magS[mc - d1] & 0xFFF;
        int n2 = magS[mc + d1] & 0xFFF;
        bool keep = (mag >= n1) && (mag > n2) && (gyp > 0) && (gyp < HH - 1);
        bool weak = keep && (mag > 100);
        bool strong = keep && (mag > 200);
        u64 ww = __ballot(weak);
        u64 sw = __ballot(strong);
        if (lane == 0) {
            u64 m = ~0ull;
            if (x0 == 0) m &= ~1ull;
            if (x0 + 64 == WW) m &= ~(1ull << 63);
            wRow[rr] = ww & m;
            sRow[rr] = sw & m;
        }
    }
    for (int i = tid; i < 4097; i += 512) { fl[i] = i; touched[i] = 0; }
    __syncthreads();

    // ---- local unions: thread -> (row r, octant o); nodes are pixel+1 ----
    {
        const int r = tid >> 3, o = tid & 7;
        const u64 omask = 0xFFull << (o * 8);
        const u64 w = wRow[r];
        const u64 above = r ? wRow[r - 1] : 0;
        const int base = r * 64 + 1;
        u64 m;
        m = (w & (w >> 1)) & omask;
        while (m) { int b = __builtin_ctzll(m); m &= m - 1; uniteL(fl, base + b, base + b + 1); }
        m = (w & above) & omask;
        while (m) { int b = __builtin_ctzll(m); m &= m - 1; uniteL(fl, base + b, base - 64 + b); }
        m = (w & (above << 1)) & omask;
        while (m) { int b = __builtin_ctzll(m); m &= m - 1; uniteL(fl, base + b, base - 64 + b - 1); }
        m = (w & (above >> 1)) & omask;
        while (m) { int b = __builtin_ctzll(m); m &= m - 1; uniteL(fl, base + b, base - 64 + b + 1); }
        m = sRow[r] & omask;                   // strong -> virtual node 0
        while (m) { int b = __builtin_ctzll(m); m &= m - 1; uniteL(fl, 0, base + b); }
    }
    __syncthreads();

    // ---- mark border-touching comps (rows 0/63, cols 0/63 weak px) ----
    if (tid < 256) {
        int grp = tid >> 6;
        int ln = tid & 63;
        int node = -1;
        if (grp == 0)      { if ((wRow[0]  >> ln) & 1ull) node = ln + 1; }
        else if (grp == 1) { if ((wRow[63] >> ln) & 1ull) node = 63 * 64 + ln + 1; }
        else if (grp == 2) { if (wRow[ln] & 1ull)         node = ln * 64 + 1; }
        else               { if (wRow[ln] >> 63)          node = ln * 64 + 63 + 1; }
        if (node > 0) touched[findRootL(fl, node)] = 1;
    }
    __syncthreads();

    // ---- write-out: edge=(root==0); pend=weak&!edge&touched; sparse f ----
    for (int k = 0; k < 8; ++k) {
        int i = k * 512 + tid;
        int rr = i >> 6, cc = i & 63;
        int g = (y0 + rr) * WW + x0 + cc;
        bool edge = false, pend = false;
        if ((wRow[rr] >> cc) & 1ull) {
            bool onBorder = (rr == 0) | (rr == 63) | (cc == 0) | (cc == 63);
            int rt = findRootL(fl, i + 1);
            if (rt == 0) {
                edge = true;
                if (onBorder) f[g] = 0;
            } else if (touched[rt]) {
                pend = true;
                f[g] = (y0 + ((rt - 1) >> 6)) * WW + x0 + ((rt - 1) & 63);
            }
        }
        u64 eb = __ballot(edge);
        u64 pb = __ballot(pend);
        if (lane == 0) {
            int widx = (y0 + rr) * WPR + (x0 >> 6);
            edgeBits[widx] = eb;
            pendBits[widx] = pb;
        }
    }
    if (tid < 64) weakG[(y0 + tid) * WPR + blockIdx.x] = wRow[tid];
}

// ---------------- Kernel 2: cross-tile boundary unions, 1 thread per boundary px ----
__global__ __launch_bounds__(256) void canny_boundary(
    const u64* __restrict__ weakG, int* __restrict__ f)
{
    int t = blockIdx.x * 256 + threadIdx.x;
    if (t < 65536) {
        int y = t >> 5, c = t & 31;
        if (c == 31) return;
        u64 w0 = weakG[y * WPR + c];
        u64 w1 = weakG[y * WPR + c + 1];
        int a = (int)(w0 >> 63) & 1, b = (int)w1 & 1;
        if (!(a | b)) return;
        int p63 = y * WW + c * 64 + 63;
        int p64 = p63 + 1;
        if (a & b) unite(f, p63, p64);
        if (y < HH - 1) {
            u64 w0d = weakG[(y + 1) * WPR + c];
            u64 w1d = weakG[(y + 1) * WPR + c + 1];
            if (a && (w1d & 1ull)) unite(f, p63, p64 + WW);
            if (b && (w0d >> 63)) unite(f, p64, p63 + WW);
        }
    } else {
        int idx = t - 65536;
        if (idx >= 31 * 2048) return;
        int y = 63 + (idx >> 11) * 64;
        int xx = idx & 2047;
        u64 w = weakG[y * WPR + (xx >> 6)];
        if (!((w >> (xx & 63)) & 1ull)) return;
        int p = y * WW + xx;
        u64 wd = weakG[(y + 1) * WPR + (xx >> 6)];
        if ((wd >> (xx & 63)) & 1ull) unite(f, p, p + WW);
        if (xx > 0) {
            u64 wl = weakG[(y + 1) * WPR + ((xx - 1) >> 6)];
            if ((wl >> ((xx - 1) & 63)) & 1ull) unite(f, p, p + WW - 1);
        }
        if (xx < WW - 1) {
            u64 wr = weakG[(y + 1) * WPR + ((xx + 1) >> 6)];
            if ((wr >> ((xx + 1) & 63)) & 1ull) unite(f, p, p + WW + 1);
        }
    }
}

// ---------------- Kernel 3: finalize pend px + coalesced 3ch fp32 write ------------
__global__ __launch_bounds__(256) void canny_edgefuse(
    const u64* __restrict__ edgeBits, const u64* __restrict__ pendBits,
    const int* __restrict__ f, float* __restrict__ out)
{
    __shared__ unsigned short eS[256];
    const int tid = threadIdx.x;
    const int B = blockIdx.x * 4096;
    const int px0 = B + tid * 16;
    u64 ew = edgeBits[px0 >> 6];
    u64 pw = pendBits[px0 >> 6];
    const int sh = px0 & 63;
    u32 be = (u32)(ew >> sh) & 0xFFFFu;
    u32 bp = (u32)(pw >> sh) & 0xFFFFu;
    if (bp) {
        int lastp = -1, laste = 0;
        do {
            int b = __builtin_ctz(bp); bp &= bp - 1;
            int v = __hip_atomic_load(&f[px0 + b], __ATOMIC_RELAXED, __HIP_MEMORY_SCOPE_AGENT);
            int ed;
            if (v == 0) ed = 1;
            else if (v == px0 + b) ed = 0;
            else if (v == lastp) ed = laste;
            else { ed = (findRootRO(f, v) == 0); lastp = v; laste = ed; }
            be |= (u32)ed << b;
        } while (bp);
    }
    eS[tid] = (unsigned short)be;
    __syncthreads();

    #pragma unroll
    for (int ch = 0; ch < 3; ++ch) {
        #pragma unroll
        for (int j = 0; j < 4; ++j) {
            int idx = j * 256 + tid;
            u32 eb = (u32)(eS[idx >> 2] >> ((idx & 3) * 4)) & 0xFu;
            float4 v;
            v.x = (float)(eb & 1u);
            v.y = (float)((eb >> 1) & 1u);
            v.z = (float)((eb >> 2) & 1u);
            v.w = (float)((eb >> 3) & 1u);
            *reinterpret_cast<float4*>(out + (size_t)ch * NPIX + B + idx * 4) = v;
        }
    }
}

// ---------------- Fallback path (small ws): prep + proven cooperative hysteresis ----
__global__ __launch_bounds__(256) void canny_prep(
    const float* __restrict__ x, u64* __restrict__ weakG,
    u64* __restrict__ strongG, unsigned int* __restrict__ flags)
{
    __shared__ int imgS[20][68];
    __shared__ int magS[18][68];
    const int tid = threadIdx.x;
    const int tx0 = blockIdx.x * 64;
    const int ty0 = blockIdx.y * 16;

    if (flags && blockIdx.x == 0 && blockIdx.y == 0 && tid < 2) flags[tid] = 0u;

    for (int idx = tid; idx < 20 * 68; idx += 256) {
        int r = idx / 68, c = idx - r * 68;
        int gy = ty0 - 2 + r; gy = gy < 0 ? 0 : (gy > HH - 1 ? HH - 1 : gy);
        int gx = tx0 - 2 + c; gx = gx < 0 ? 0 : (gx > WW - 1 ? WW - 1 : gx);
        float v = floorf(x[gy * WW + gx] * 255.0f);
        v = fminf(fmaxf(v, 0.0f), 255.0f);
        imgS[r][c] = (int)v;
    }
    __syncthreads();

    for (int idx = tid; idx < 18 * 66; idx += 256) {
        int r = idx / 66, c = idx - r * 66;
        int a00 = imgS[r][c],     a01 = imgS[r][c + 1],     a02 = imgS[r][c + 2];
        int a10 = imgS[r + 1][c],                           a12 = imgS[r + 1][c + 2];
        int a20 = imgS[r + 2][c], a21 = imgS[r + 2][c + 1], a22 = imgS[r + 2][c + 2];
        int gxv = (a02 + 2 * a12 + a22) - (a00 + 2 * a10 + a20);
        int gyv = (a20 + 2 * a21 + a22) - (a00 + 2 * a01 + a02);
        magS[r][c] = abs(gxv) + abs(gyv);
    }
    __syncthreads();

    const int lane = tid & 63;
    const int wv = tid >> 6;
    for (int i = 0; i < 4; ++i) {
        int rr = wv * 4 + i;
        int gyp = ty0 + rr;
        int r = rr + 1, c = lane + 1;
        int a00 = imgS[rr + 1][lane + 1], a01 = imgS[rr + 1][lane + 2], a02 = imgS[rr + 1][lane + 3];
        int a10 = imgS[rr + 2][lane + 1],                               a12 = imgS[rr + 2][lane + 3];
        int a20 = imgS[rr + 3][lane + 1], a21 = imgS[rr + 3][lane + 2], a22 = imgS[rr + 3][lane + 3];
        int gxv = (a02 + 2 * a12 + a22) - (a00 + 2 * a10 + a20);
        int gyv = (a20 + 2 * a21 + a22) - (a00 + 2 * a01 + a02);
        int mag = magS[r][c];
        int cls = dirClass(gxv, gyv);
        int n1, n2;
        if (cls == 0)      { n1 = magS[r][c + 1];     n2 = magS[r][c - 1]; }
        else if (cls == 1) { n1 = magS[r - 1][c + 1]; n2 = magS[r + 1][c - 1]; }
        else if (cls == 2) { n1 = magS[r - 1][c];     n2 = magS[r + 1][c]; }
        else               { n1 = magS[r - 1][c - 1]; n2 = magS[r + 1][c + 1]; }

        bool keep = (mag >= n1) && (mag > n2) && (gyp > 0) && (gyp < HH - 1);
        bool weak = keep && (mag > 100);
        bool strong = keep && (mag > 200);
        u64 ww = __ballot(weak);
        u64 sw = __ballot(strong);
        if (lane == 0) {
            u64 mm = ~0ull;
            if (tx0 == 0) mm &= ~1ull;
            if (tx0 + 64 == WW) mm &= ~(1ull << 63);
            int widx = gyp * WPR + (tx0 >> 6);
            weakG[widx] = ww & mm;
            strongG[widx] = sw & mm;
        }
    }
}

__global__ __launch_bounds__(256) void canny_hyst(
    const u64* __restrict__ weakG, u64* __restrict__ edgeG,
    unsigned int* __restrict__ flags, float* __restrict__ out)
{
    cg::grid_group grid = cg::this_grid();
    const int tid = threadIdx.x;
    const int b = blockIdx.x;
    const int r = tid >> 5;
    const int c = tid & 31;
    const int row0 = b * 8;
    __shared__ u64 weakL[8][32];
    __shared__ u64 edgeL[10][32];
    __shared__ int sChg[2];
    __shared__ int sAny;

    weakL[r][c] = weakG[(row0 + r) * WPR + c];
    edgeL[r + 1][c] = edgeG[(row0 + r) * WPR + c];

    int iter = 0;
    for (;;) {
        if (tid < 32) {
            u64 v = 0;
            if (b > 0) v = __hip_atomic_load(&edgeG[(row0 - 1) * WPR + tid],
                                             __ATOMIC_RELAXED, __HIP_MEMORY_SCOPE_AGENT);
            edgeL[0][tid] = v;
        } else if (tid < 64) {
            int cc = tid - 32;
            u64 v = 0;
            if (b < (int)gridDim.x - 1)
                v = __hip_atomic_load(&edgeG[(row0 + 8) * WPR + cc],
                                      __ATOMIC_RELAXED, __HIP_MEMORY_SCOPE_AGENT);
            edgeL[9][cc] = v;
        }
        if (tid == 0) sAny = 0;
        if (tid < 2) sChg[tid] = 0;
        __syncthreads();

        int p = 0;
        for (;;) {
            u64 up = edgeL[r][c],     upl = c ? edgeL[r][c - 1] : 0,     upr = (c < 31) ? edgeL[r][c + 1] : 0;
            u64 mi = edgeL[r + 1][c], mil = c ? edgeL[r + 1][c - 1] : 0, mir = (c < 31) ? edgeL[r + 1][c + 1] : 0;
            u64 dn = edgeL[r + 2][c], dnl = c ? edgeL[r + 2][c - 1] : 0, dnr = (c < 31) ? edgeL[r + 2][c + 1] : 0;
            u64 A = up | (up << 1) | (up >> 1) | (upl >> 63) | (upr << 63);
            u64 B = mi | (mi << 1) | (mi >> 1) | (mil >> 63) | (mir << 63);
            u64 C = dn | (dn << 1) | (dn >> 1) | (dnl >> 63) | (dnr << 63);
            u64 ne = mi | (weakL[r][c] & (A | B | C));
            bool chg = (ne != mi);
            __syncthreads();
            edgeL[r + 1][c] = ne;
            if (chg) { sChg[p] = 1; sAny = 1; }
            if (tid == 0) sChg[p ^ 1] = 0;
            __syncthreads();
            if (!sChg[p]) break;
            p ^= 1;
        }

        if (sAny) edgeG[(row0 + r) * WPR + c] = edgeL[r + 1][c];
        if (sAny && tid == 0) atomicOr(&flags[iter & 1], 1u);
        __threadfence();
        grid.sync();
        unsigned fl2 = __hip_atomic_load(&flags[iter & 1], __ATOMIC_ACQUIRE, __HIP_MEMORY_SCOPE_AGENT);
        if (tid == 0) flags[(iter + 1) & 1] = 0u;
        __threadfence();
        grid.sync();
        if (fl2 == 0) break;
        ++iter;
    }

    for (int chn = 0; chn < 3; ++chn) {
        for (int rr = 0; rr < 8; ++rr) {
            size_t base2 = ((size_t)chn * HH + (size_t)(row0 + rr)) * WW;
            for (int k = tid; k < 512; k += 256) {
                u64 w = edgeL[rr + 1][k >> 4];
                int sh = (k & 15) * 4;
                float4 v;
                v.x = (float)((w >> sh) & 1ull);
                v.y = (float)((w >> (sh + 1)) & 1ull);
                v.z = (float)((w >> (sh + 2)) & 1ull);
                v.w = (float)((w >> (sh + 3)) & 1ull);
                *reinterpret_cast<float4*>(out + base2 + (size_t)k * 4) = v;
            }
        }
    }
}

extern "C" void kernel_launch(void* const* d_in, const int* in_sizes, int n_in,
                              void* d_out, int out_size, void* d_ws, size_t ws_size,
                              hipStream_t stream) {
    const float* x = (const float*)d_in[0];
    float* out = (float*)d_out;

    const size_t BM = (size_t)NWORDS * 8;          // 512 KB per bitmap
    const size_t need = 3 * BM + (size_t)NPIX * 4; // weak+edge+pend bitmaps + labels

    if (ws_size >= need) {
        u64* weakG    = (u64*)d_ws;
        u64* edgeBits = weakG + NWORDS;
        u64* pendBits = edgeBits + NWORDS;
        int* f = (int*)(pendBits + NWORDS);

        hipLaunchKernelGGL(canny_tile, dim3(32, 32), dim3(512), 0, stream,
                           x, weakG, edgeBits, pendBits, f);
        hipLaunchKernelGGL(canny_boundary, dim3((65536 + 31 * 2048 + 255) / 256), dim3(256),
                           0, stream, weakG, f);
        hipLaunchKernelGGL(canny_edgefuse, dim3(NPIX / 4096), dim3(256), 0, stream,
                           edgeBits, pendBits, f, out);
    } else {
        u64* edgeG = (u64*)d_ws;
        u64* weakG = edgeG + NWORDS;
        unsigned int* flags = (unsigned int*)(weakG + NWORDS);
        hipLaunchKernelGGL(canny_prep, dim3(WW / 64, HH / 16), dim3(256), 0, stream,
                           x, weakG, edgeG, flags);
        void* args[] = { (void*)&weakG, (void*)&edgeG, (void*)&flags, (void*)&out };
        hipLaunchCooperativeKernel((void*)canny_hyst, dim3(256), dim3(256), args, 0, stream);
    }
}

// Round 10
// 121.897 us; speedup vs baseline: 1.0186x; 1.0186x over previous
//
#include <hip/hip_runtime.h>
#include <hip/hip_cooperative_groups.h>

namespace cg = cooperative_groups;

#define HH 2048
#define WW 2048
#define WPR 32            // 64-bit words per image row
#define NPIX (HH * WW)
#define NWORDS (HH * WPR)

typedef unsigned long long u64;
typedef unsigned int u32;

// ---------------- global union-find (ECL-CC style, lock-free) ----------------
__device__ inline int findRoot(int* __restrict__ f, int i) {
    int p = __hip_atomic_load(&f[i], __ATOMIC_RELAXED, __HIP_MEMORY_SCOPE_AGENT);
    while (p != i) {
        int gp = __hip_atomic_load(&f[p], __ATOMIC_RELAXED, __HIP_MEMORY_SCOPE_AGENT);
        if (gp != p)
            __hip_atomic_store(&f[i], gp, __ATOMIC_RELAXED, __HIP_MEMORY_SCOPE_AGENT);
        i = p; p = gp;
    }
    return i;
}

__device__ inline void unite(int* __restrict__ f, int a, int b) {
    int ra = findRoot(f, a), rb = findRoot(f, b);
    while (ra != rb) {
        if (ra > rb) { int t = ra; ra = rb; rb = t; }
        int old = atomicCAS(&f[rb], rb, ra);
        if (old == rb || old == ra) return;
        rb = findRoot(f, old);
    }
}

__device__ inline int findRootRO(const int* __restrict__ f, int i) {
    int p = __hip_atomic_load(&f[i], __ATOMIC_RELAXED, __HIP_MEMORY_SCOPE_AGENT);
    while (true) {
        int gp = __hip_atomic_load(&f[p], __ATOMIC_RELAXED, __HIP_MEMORY_SCOPE_AGENT);
        if (gp == p) return p;
        p = gp;
    }
}

// ---------------- LDS-local union-find ----------------
__device__ inline int findRootL(volatile int* fl, int i) {
    int p = fl[i];
    while (p != i) {
        int gp = fl[p];
        if (gp != p) fl[i] = gp;
        i = p; p = gp;
    }
    return i;
}

__device__ inline void uniteL(int* fl, int a, int b) {
    int ra = findRootL(fl, a), rb = findRootL(fl, b);
    while (ra != rb) {
        if (ra > rb) { int t = ra; ra = rb; rb = t; }
        int old = atomicCAS(&fl[rb], rb, ra);
        if (old == rb || old == ra) return;
        rb = findRootL(fl, old);
    }
}

// exact direction class (branchy form, used by fallback prep only)
__device__ inline int dirClass(int gxv, int gyv) {
    int ay = gyv, ax = gxv;
    if (ay < 0) { ay = -ay; ax = -ax; }
    if (ay == 0) return 0;
    if (ax > 0) {
        int s = ay + ax, q = 2 * ax * ax;
        if (s * s < q) return 0;
        int t = ay - ax;
        return (t < 0 || t * t < q) ? 1 : 2;
    }
    if (ax == 0) return 2;
    int h = -ax, s = ay + h, q = 2 * h * h;
    if (s * s < q) return 0;
    int t = ay - h;
    return (t > 0 && t * t > q) ? 2 : 3;
}

// ---------------- Kernel 1 (fused): quantize+Sobel+NMS+thresholds+LOCAL CC ----------
// 64x64 tile per block, 512 threads. Local node 0 is a VIRTUAL strong super-root.
// f written SPARSELY (only entries later chases can read). f[0]=0 by block (0,0).
__global__ __launch_bounds__(512) void canny_tile(
    const float* __restrict__ x, u64* __restrict__ weakG,
    u64* __restrict__ edgeBits, u64* __restrict__ pendBits, int* __restrict__ f)
{
    __shared__ int imgS[68 * 68];            // quantized img, halo 2; REUSED as fl[4097]
    __shared__ unsigned short magS[66 * 66]; // (cls<<12) | mag  (mag<=2040<4096)
    __shared__ u64 wRow[64], sRow[64];
    __shared__ unsigned char touched[4097];
    int* fl = imgS;

    const int tid = threadIdx.x;
    const int x0 = blockIdx.x * 64;
    const int y0 = blockIdx.y * 64;

    if (blockIdx.x == 0 && blockIdx.y == 0 && tid == 0) f[0] = 0;

    // ---- stage 68x68 quantized image. (int)(v*255) == floor for v in [0,1]. ----
    if (x0 >= 4 && x0 + 68 <= WW) {
        for (int t = tid; t < 18 * 68; t += 512) {
            int r = t / 18, k = t - r * 18;
            int gy = y0 - 2 + r; gy = gy < 0 ? 0 : (gy > HH - 1 ? HH - 1 : gy);
            float4 v = *reinterpret_cast<const float4*>(x + (size_t)gy * WW + (x0 - 4) + 4 * k);
            int c0 = 4 * k - 2;
            if (c0 >= 0)                 imgS[r * 68 + c0]     = (int)(v.x * 255.0f);
            if ((unsigned)(c0 + 1) < 68) imgS[r * 68 + c0 + 1] = (int)(v.y * 255.0f);
            if ((unsigned)(c0 + 2) < 68) imgS[r * 68 + c0 + 2] = (int)(v.z * 255.0f);
            if (c0 + 3 < 68)             imgS[r * 68 + c0 + 3] = (int)(v.w * 255.0f);
        }
    } else {
        for (int idx = tid; idx < 68 * 68; idx += 512) {
            int r = idx / 68, c = idx - r * 68;
            int gy = y0 - 2 + r; gy = gy < 0 ? 0 : (gy > HH - 1 ? HH - 1 : gy);
            int gx = x0 - 2 + c; gx = gx < 0 ? 0 : (gx > WW - 1 ? WW - 1 : gx);
            imgS[idx] = (int)(x[(size_t)gy * WW + gx] * 255.0f);
        }
    }
    __syncthreads();

    // ---- Sobel once per 66x66 item: pack (cls<<12)|mag, BRANCHLESS class ----
    // cls = (mag^2 < 2X^2) ? 0 : (mag^2 < 2A^2) ? 2 : ((gx^gy)<0 ? 3 : 1)
    // (A=|gy|, X=|gx|, mag=A+X<=2040 -> all squares int32-exact; boundary
    //  equalities unreachable for integers; gx=gy=0 -> cls1 but mag=0 never kept)
    for (int idx = tid; idx < 66 * 66; idx += 512) {
        int r = idx / 66, c = idx - r * 66;
        int i0 = r * 68 + c;
        int a00 = imgS[i0],       a01 = imgS[i0 + 1],   a02 = imgS[i0 + 2];
        int a10 = imgS[i0 + 68],                        a12 = imgS[i0 + 70];
        int a20 = imgS[i0 + 136], a21 = imgS[i0 + 137], a22 = imgS[i0 + 138];
        int gxv = (a02 + 2 * a12 + a22) - (a00 + 2 * a10 + a20);
        int gyv = (a20 + 2 * a21 + a22) - (a00 + 2 * a01 + a02);
        int A = abs(gyv), X = abs(gxv);
        int mag = A + X;
        int m2 = mag * mag;
        int cls = (m2 < 2 * X * X) ? 0 : (m2 < 2 * A * A) ? 2 : (((gxv ^ gyv) < 0) ? 3 : 1);
        magS[idx] = (unsigned short)((cls << 12) | mag);
    }
    __syncthreads();   // imgS dead (NMS reads only magS) -> fl aliases imgS

    // ---- NMS + thresholds; fl/touched init in same phase ----
    const int lane = tid & 63;
    const int wv = tid >> 6;
    for (int i = 0; i < 8; ++i) {
        int rr = wv * 8 + i;
        int gyp = y0 + rr;
        int mc = (rr + 1) * 66 + lane + 1;
        int mv = magS[mc];
        int cls = mv >> 12;
        int mag = mv & 0xFFF;
        int d1 = (cls == 0) ? -1 : 64 + cls;
        int n1 = magS[mc - d1] & 0xFFF;
        int n2 = magS[mc + d1] & 0xFFF;
        bool keep = (mag >= n1) && (mag > n2) && (gyp > 0) && (gyp < HH - 1);
        bool weak = keep && (mag > 100);
        bool strong = keep && (mag > 200);
        u64 ww = __ballot(weak);
        u64 sw = __ballot(strong);
        if (lane == 0) {
            u64 m = ~0ull;
            if (x0 == 0) m &= ~1ull;
            if (x0 + 64 == WW) m &= ~(1ull << 63);
            wRow[rr] = ww & m;
            sRow[rr] = sw & m;
        }
    }
    for (int i = tid; i < 4097; i += 512) { fl[i] = i; touched[i] = 0; }
    __syncthreads();

    // ---- local unions: thread -> (row r, octant o); nodes are pixel+1 ----
    {
        const int r = tid >> 3, o = tid & 7;
        const u64 omask = 0xFFull << (o * 8);
        const u64 w = wRow[r];
        const u64 above = r ? wRow[r - 1] : 0;
        const int base = r * 64 + 1;
        u64 m;
        m = (w & (w >> 1)) & omask;
        while (m) { int b = __builtin_ctzll(m); m &= m - 1; uniteL(fl, base + b, base + b + 1); }
        m = (w & above) & omask;
        while (m) { int b = __builtin_ctzll(m); m &= m - 1; uniteL(fl, base + b, base - 64 + b); }
        m = (w & (above << 1)) & omask;
        while (m) { int b = __builtin_ctzll(m); m &= m - 1; uniteL(fl, base + b, base - 64 + b - 1); }
        m = (w & (above >> 1)) & omask;
        while (m) { int b = __builtin_ctzll(m); m &= m - 1; uniteL(fl, base + b, base - 64 + b + 1); }
        m = sRow[r] & omask;                   // strong -> virtual node 0
        while (m) { int b = __builtin_ctzll(m); m &= m - 1; uniteL(fl, 0, base + b); }
    }
    __syncthreads();

    // ---- mark border-touching comps (rows 0/63, cols 0/63 weak px) ----
    if (tid < 256) {
        int grp = tid >> 6;
        int ln = tid & 63;
        int node = -1;
        if (grp == 0)      { if ((wRow[0]  >> ln) & 1ull) node = ln + 1; }
        else if (grp == 1) { if ((wRow[63] >> ln) & 1ull) node = 63 * 64 + ln + 1; }
        else if (grp == 2) { if (wRow[ln] & 1ull)         node = ln * 64 + 1; }
        else               { if (wRow[ln] >> 63)          node = ln * 64 + 63 + 1; }
        if (node > 0) touched[findRootL(fl, node)] = 1;
    }
    __syncthreads();

    // ---- write-out: edge=(root==0); pend=weak&!edge&touched; sparse f ----
    for (int k = 0; k < 8; ++k) {
        int i = k * 512 + tid;
        int rr = i >> 6, cc = i & 63;
        int g = (y0 + rr) * WW + x0 + cc;
        bool edge = false, pend = false;
        if ((wRow[rr] >> cc) & 1ull) {
            bool onBorder = (rr == 0) | (rr == 63) | (cc == 0) | (cc == 63);
            int rt = findRootL(fl, i + 1);
            if (rt == 0) {
                edge = true;
                if (onBorder) f[g] = 0;
            } else if (touched[rt]) {
                pend = true;
                f[g] = (y0 + ((rt - 1) >> 6)) * WW + x0 + ((rt - 1) & 63);
            }
        }
        u64 eb = __ballot(edge);
        u64 pb = __ballot(pend);
        if (lane == 0) {
            int widx = (y0 + rr) * WPR + (x0 >> 6);
            edgeBits[widx] = eb;
            pendBits[widx] = pb;
        }
    }
    if (tid < 64) weakG[(y0 + tid) * WPR + blockIdx.x] = wRow[tid];
}

// ---------------- Kernel 2: cross-tile boundary unions, 1 thread per boundary px ----
__global__ __launch_bounds__(256) void canny_boundary(
    const u64* __restrict__ weakG, int* __restrict__ f)
{
    int t = blockIdx.x * 256 + threadIdx.x;
    if (t < 65536) {
        int y = t >> 5, c = t & 31;
        if (c == 31) return;
        u64 w0 = weakG[y * WPR + c];
        u64 w1 = weakG[y * WPR + c + 1];
        int a = (int)(w0 >> 63) & 1, b = (int)w1 & 1;
        if (!(a | b)) return;
        int p63 = y * WW + c * 64 + 63;
        int p64 = p63 + 1;
        if (a & b) unite(f, p63, p64);
        if (y < HH - 1) {
            u64 w0d = weakG[(y + 1) * WPR + c];
            u64 w1d = weakG[(y + 1) * WPR + c + 1];
            if (a && (w1d & 1ull)) unite(f, p63, p64 + WW);
            if (b && (w0d >> 63)) unite(f, p64, p63 + WW);
        }
    } else {
        int idx = t - 65536;
        if (idx >= 31 * 2048) return;
        int y = 63 + (idx >> 11) * 64;
        int xx = idx & 2047;
        u64 w = weakG[y * WPR + (xx >> 6)];
        if (!((w >> (xx & 63)) & 1ull)) return;
        int p = y * WW + xx;
        u64 wd = weakG[(y + 1) * WPR + (xx >> 6)];
        if ((wd >> (xx & 63)) & 1ull) unite(f, p, p + WW);
        if (xx > 0) {
            u64 wl = weakG[(y + 1) * WPR + ((xx - 1) >> 6)];
            if ((wl >> ((xx - 1) & 63)) & 1ull) unite(f, p, p + WW - 1);
        }
        if (xx < WW - 1) {
            u64 wr = weakG[(y + 1) * WPR + ((xx + 1) >> 6)];
            if ((wr >> ((xx + 1) & 63)) & 1ull) unite(f, p, p + WW + 1);
        }
    }
}

// ---------------- Kernel 3: finalize pend px + coalesced 3ch fp32 write ------------
__global__ __launch_bounds__(256) void canny_edgefuse(
    const u64* __restrict__ edgeBits, const u64* __restrict__ pendBits,
    const int* __restrict__ f, float* __restrict__ out)
{
    __shared__ unsigned short eS[256];
    const int tid = threadIdx.x;
    const int B = blockIdx.x * 4096;
    const int px0 = B + tid * 16;
    u64 ew = edgeBits[px0 >> 6];
    u64 pw = pendBits[px0 >> 6];
    const int sh = px0 & 63;
    u32 be = (u32)(ew >> sh) & 0xFFFFu;
    u32 bp = (u32)(pw >> sh) & 0xFFFFu;
    if (bp) {
        int lastp = -1, laste = 0;
        do {
            int b = __builtin_ctz(bp); bp &= bp - 1;
            int v = __hip_atomic_load(&f[px0 + b], __ATOMIC_RELAXED, __HIP_MEMORY_SCOPE_AGENT);
            int ed;
            if (v == 0) ed = 1;
            else if (v == px0 + b) ed = 0;
            else if (v == lastp) ed = laste;
            else { ed = (findRootRO(f, v) == 0); lastp = v; laste = ed; }
            be |= (u32)ed << b;
        } while (bp);
    }
    eS[tid] = (unsigned short)be;
    __syncthreads();

    #pragma unroll
    for (int ch = 0; ch < 3; ++ch) {
        #pragma unroll
        for (int j = 0; j < 4; ++j) {
            int idx = j * 256 + tid;
            u32 eb = (u32)(eS[idx >> 2] >> ((idx & 3) * 4)) & 0xFu;
            float4 v;
            v.x = (float)(eb & 1u);
            v.y = (float)((eb >> 1) & 1u);
            v.z = (float)((eb >> 2) & 1u);
            v.w = (float)((eb >> 3) & 1u);
            *reinterpret_cast<float4*>(out + (size_t)ch * NPIX + B + idx * 4) = v;
        }
    }
}

// ---------------- Fallback path (small ws): prep + proven cooperative hysteresis ----
__global__ __launch_bounds__(256) void canny_prep(
    const float* __restrict__ x, u64* __restrict__ weakG,
    u64* __restrict__ strongG, unsigned int* __restrict__ flags)
{
    __shared__ int imgS[20][68];
    __shared__ int magS[18][68];
    const int tid = threadIdx.x;
    const int tx0 = blockIdx.x * 64;
    const int ty0 = blockIdx.y * 16;

    if (flags && blockIdx.x == 0 && blockIdx.y == 0 && tid < 2) flags[tid] = 0u;

    for (int idx = tid; idx < 20 * 68; idx += 256) {
        int r = idx / 68, c = idx - r * 68;
        int gy = ty0 - 2 + r; gy = gy < 0 ? 0 : (gy > HH - 1 ? HH - 1 : gy);
        int gx = tx0 - 2 + c; gx = gx < 0 ? 0 : (gx > WW - 1 ? WW - 1 : gx);
        float v = floorf(x[gy * WW + gx] * 255.0f);
        v = fminf(fmaxf(v, 0.0f), 255.0f);
        imgS[r][c] = (int)v;
    }
    __syncthreads();

    for (int idx = tid; idx < 18 * 66; idx += 256) {
        int r = idx / 66, c = idx - r * 66;
        int a00 = imgS[r][c],     a01 = imgS[r][c + 1],     a02 = imgS[r][c + 2];
        int a10 = imgS[r + 1][c],                           a12 = imgS[r + 1][c + 2];
        int a20 = imgS[r + 2][c], a21 = imgS[r + 2][c + 1], a22 = imgS[r + 2][c + 2];
        int gxv = (a02 + 2 * a12 + a22) - (a00 + 2 * a10 + a20);
        int gyv = (a20 + 2 * a21 + a22) - (a00 + 2 * a01 + a02);
        magS[r][c] = abs(gxv) + abs(gyv);
    }
    __syncthreads();

    const int lane = tid & 63;
    const int wv = tid >> 6;
    for (int i = 0; i < 4; ++i) {
        int rr = wv * 4 + i;
        int gyp = ty0 + rr;
        int r = rr + 1, c = lane + 1;
        int a00 = imgS[rr + 1][lane + 1], a01 = imgS[rr + 1][lane + 2], a02 = imgS[rr + 1][lane + 3];
        int a10 = imgS[rr + 2][lane + 1],                               a12 = imgS[rr + 2][lane + 3];
        int a20 = imgS[rr + 3][lane + 1], a21 = imgS[rr + 3][lane + 2], a22 = imgS[rr + 3][lane + 3];
        int gxv = (a02 + 2 * a12 + a22) - (a00 + 2 * a10 + a20);
        int gyv = (a20 + 2 * a21 + a22) - (a00 + 2 * a01 + a02);
        int mag = magS[r][c];
        int cls = dirClass(gxv, gyv);
        int n1, n2;
        if (cls == 0)      { n1 = magS[r][c + 1];     n2 = magS[r][c - 1]; }
        else if (cls == 1) { n1 = magS[r - 1][c + 1]; n2 = magS[r + 1][c - 1]; }
        else if (cls == 2) { n1 = magS[r - 1][c];     n2 = magS[r + 1][c]; }
        else               { n1 = magS[r - 1][c - 1]; n2 = magS[r + 1][c + 1]; }

        bool keep = (mag >= n1) && (mag > n2) && (gyp > 0) && (gyp < HH - 1);
        bool weak = keep && (mag > 100);
        bool strong = keep && (mag > 200);
        u64 ww = __ballot(weak);
        u64 sw = __ballot(strong);
        if (lane == 0) {
            u64 mm = ~0ull;
            if (tx0 == 0) mm &= ~1ull;
            if (tx0 + 64 == WW) mm &= ~(1ull << 63);
            int widx = gyp * WPR + (tx0 >> 6);
            weakG[widx] = ww & mm;
            strongG[widx] = sw & mm;
        }
    }
}

__global__ __launch_bounds__(256) void canny_hyst(
    const u64* __restrict__ weakG, u64* __restrict__ edgeG,
    unsigned int* __restrict__ flags, float* __restrict__ out)
{
    cg::grid_group grid = cg::this_grid();
    const int tid = threadIdx.x;
    const int b = blockIdx.x;
    const int r = tid >> 5;
    const int c = tid & 31;
    const int row0 = b * 8;
    __shared__ u64 weakL[8][32];
    __shared__ u64 edgeL[10][32];
    __shared__ int sChg[2];
    __shared__ int sAny;

    weakL[r][c] = weakG[(row0 + r) * WPR + c];
    edgeL[r + 1][c] = edgeG[(row0 + r) * WPR + c];

    int iter = 0;
    for (;;) {
        if (tid < 32) {
            u64 v = 0;
            if (b > 0) v = __hip_atomic_load(&edgeG[(row0 - 1) * WPR + tid],
                                             __ATOMIC_RELAXED, __HIP_MEMORY_SCOPE_AGENT);
            edgeL[0][tid] = v;
        } else if (tid < 64) {
            int cc = tid - 32;
            u64 v = 0;
            if (b < (int)gridDim.x - 1)
                v = __hip_atomic_load(&edgeG[(row0 + 8) * WPR + cc],
                                      __ATOMIC_RELAXED, __HIP_MEMORY_SCOPE_AGENT);
            edgeL[9][cc] = v;
        }
        if (tid == 0) sAny = 0;
        if (tid < 2) sChg[tid] = 0;
        __syncthreads();

        int p = 0;
        for (;;) {
            u64 up = edgeL[r][c],     upl = c ? edgeL[r][c - 1] : 0,     upr = (c < 31) ? edgeL[r][c + 1] : 0;
            u64 mi = edgeL[r + 1][c], mil = c ? edgeL[r + 1][c - 1] : 0, mir = (c < 31) ? edgeL[r + 1][c + 1] : 0;
            u64 dn = edgeL[r + 2][c], dnl = c ? edgeL[r + 2][c - 1] : 0, dnr = (c < 31) ? edgeL[r + 2][c + 1] : 0;
            u64 A = up | (up << 1) | (up >> 1) | (upl >> 63) | (upr << 63);
            u64 B = mi | (mi << 1) | (mi >> 1) | (mil >> 63) | (mir << 63);
            u64 C = dn | (dn << 1) | (dn >> 1) | (dnl >> 63) | (dnr << 63);
            u64 ne = mi | (weakL[r][c] & (A | B | C));
            bool chg = (ne != mi);
            __syncthreads();
            edgeL[r + 1][c] = ne;
            if (chg) { sChg[p] = 1; sAny = 1; }
            if (tid == 0) sChg[p ^ 1] = 0;
            __syncthreads();
            if (!sChg[p]) break;
            p ^= 1;
        }

        if (sAny) edgeG[(row0 + r) * WPR + c] = edgeL[r + 1][c];
        if (sAny && tid == 0) atomicOr(&flags[iter & 1], 1u);
        __threadfence();
        grid.sync();
        unsigned fl2 = __hip_atomic_load(&flags[iter & 1], __ATOMIC_ACQUIRE, __HIP_MEMORY_SCOPE_AGENT);
        if (tid == 0) flags[(iter + 1) & 1] = 0u;
        __threadfence();
        grid.sync();
        if (fl2 == 0) break;
        ++iter;
    }

    for (int chn = 0; chn < 3; ++chn) {
        for (int rr = 0; rr < 8; ++rr) {
            size_t base2 = ((size_t)chn * HH + (size_t)(row0 + rr)) * WW;
            for (int k = tid; k < 512; k += 256) {
                u64 w = edgeL[rr + 1][k >> 4];
                int sh = (k & 15) * 4;
                float4 v;
                v.x = (float)((w >> sh) & 1ull);
                v.y = (float)((w >> (sh + 1)) & 1ull);
                v.z = (float)((w >> (sh + 2)) & 1ull);
                v.w = (float)((w >> (sh + 3)) & 1ull);
                *reinterpret_cast<float4*>(out + base2 + (size_t)k * 4) = v;
            }
        }
    }
}

extern "C" void kernel_launch(void* const* d_in, const int* in_sizes, int n_in,
                              void* d_out, int out_size, void* d_ws, size_t ws_size,
                              hipStream_t stream) {
    const float* x = (const float*)d_in[0];
    float* out = (float*)d_out;

    const size_t BM = (size_t)NWORDS * 8;          // 512 KB per bitmap
    const size_t need = 3 * BM + (size_t)NPIX * 4; // weak+edge+pend bitmaps + labels

    if (ws_size >= need) {
        u64* weakG    = (u64*)d_ws;
        u64* edgeBits = weakG + NWORDS;
        u64* pendBits = edgeBits + NWORDS;
        int* f = (int*)(pendBits + NWORDS);

        hipLaunchKernelGGL(canny_tile, dim3(32, 32), dim3(512), 0, stream,
                           x, weakG, edgeBits, pendBits, f);
        hipLaunchKernelGGL(canny_boundary, dim3((65536 + 31 * 2048 + 255) / 256), dim3(256),
                           0, stream, weakG, f);
        hipLaunchKernelGGL(canny_edgefuse, dim3(NPIX / 4096), dim3(256), 0, stream,
                           edgeBits, pendBits, f, out);
    } else {
        u64* edgeG = (u64*)d_ws;
        u64* weakG = edgeG + NWORDS;
        unsigned int* flags = (unsigned int*)(weakG + NWORDS);
        hipLaunchKernelGGL(canny_prep, dim3(WW / 64, HH / 16), dim3(256), 0, stream,
                           x, weakG, edgeG, flags);
        void* args[] = { (void*)&weakG, (void*)&edgeG, (void*)&flags, (void*)&out };
        hipLaunchCooperativeKernel((void*)canny_hyst, dim3(256), dim3(256), args, 0, stream);
    }
}